// Round 8
// baseline (133.000 us; speedup 1.0000x reference)
//
#include <hip/hip_runtime.h>
#include <hip/hip_fp16.h>

#define VOCAB 100000
#define HIDDEN 128
#define BATCH 1024
#define LEN 200
#define TP_V 256   // vocab-tile of the transpose kernel

typedef float f32x4 __attribute__((ext_vector_type(4)));

// ---------------------------------------------------------------------------
// MEASUREMENT ROUND: kernels identical to round 7, but each launched TWICE
// (idempotent). dur_us delta vs round 7 = transpose_time + gather_time,
// independent of harness fill/restore overhead that masks per-kernel timing.
// ---------------------------------------------------------------------------

// Kernel 1: transpose + downconvert  W f32 [HIDDEN][VOCAB] -> WT fp16 [VOCAB][HIDDEN]
__global__ __launch_bounds__(512) void wt_transpose_f16(
    const float* __restrict__ W, __half* __restrict__ WT) {
    __shared__ __half tile[TP_V][HIDDEN];
    const int v0 = blockIdx.x * TP_V;
    const int t  = threadIdx.x;

    const int vq4 = t & 63;
    const int hr  = t >> 6;    // 0..7
#pragma unroll
    for (int p = 0; p < 16; ++p) {
        const int h  = p * 8 + hr;
        const int gv = v0 + vq4 * 4;
        f32x4 f;
        if (gv + 3 < VOCAB) {
            f = __builtin_nontemporal_load(
                reinterpret_cast<const f32x4*>(&W[(size_t)h * VOCAB + gv]));
        } else {
            f[0] = (gv + 0 < VOCAB) ? W[(size_t)h * VOCAB + gv + 0] : 0.f;
            f[1] = (gv + 1 < VOCAB) ? W[(size_t)h * VOCAB + gv + 1] : 0.f;
            f[2] = (gv + 2 < VOCAB) ? W[(size_t)h * VOCAB + gv + 2] : 0.f;
            f[3] = (gv + 3 < VOCAB) ? W[(size_t)h * VOCAB + gv + 3] : 0.f;
        }
#pragma unroll
        for (int k = 0; k < 4; ++k) {
            const int v = vq4 * 4 + k;
            tile[v][h ^ ((v & 31) << 1)] = __float2half_rn(f[k]);
        }
    }
    __syncthreads();

    const int c  = t & 15;
    const int vr = t >> 4;     // 0..31
#pragma unroll
    for (int q = 0; q < 8; ++q) {
        const int v  = vr + q * 32;
        const int gv = v0 + v;
        if (gv < VOCAB) {
            __half hb[8];
            const int sw = (v & 31) << 1;
#pragma unroll
            for (int j = 0; j < 8; ++j) hb[j] = tile[v][(c * 8 + j) ^ sw];
            *reinterpret_cast<float4*>(&WT[(size_t)gv * HIDDEN + c * 8]) =
                *reinterpret_cast<const float4*>(hb);
        }
    }
}

// Kernel 2: gather-sum from fp16 WT.
__global__ __launch_bounds__(512) void bag_gather_f16(
    const int* __restrict__ ids, const __half* __restrict__ WT,
    const float* __restrict__ bias, float* __restrict__ out) {
    __shared__ int   sid[LEN];
    __shared__ float part[8][HIDDEN];   // 4 KB

    const int b = blockIdx.x;
    const int t = threadIdx.x;

    for (int l = t; l < LEN; l += 512) sid[l] = ids[b * LEN + l];
    __syncthreads();

    const int g     = t & 15;
    const int chunk = t >> 4;

    float acc[8];
#pragma unroll
    for (int k = 0; k < 8; ++k) acc[k] = 0.f;

#pragma unroll
    for (int i = 0; i < 7; ++i) {
        const int  l  = chunk + i * 32;
        const bool ok = (l < LEN);
        const int  id = ok ? sid[l] : 0;
        const float4 q = *reinterpret_cast<const float4*>(
            WT + (size_t)id * HIDDEN + g * 8);
        if (ok) {
            const __half2* h2 = reinterpret_cast<const __half2*>(&q);
#pragma unroll
            for (int k = 0; k < 4; ++k) {
                const float2 f = __half22float2(h2[k]);
                acc[2 * k + 0] += f.x;
                acc[2 * k + 1] += f.y;
            }
        }
    }

#pragma unroll
    for (int k = 0; k < 8; ++k) {
        acc[k] += __shfl_xor(acc[k], 16);
        acc[k] += __shfl_xor(acc[k], 32);
    }
    const int wave = t >> 6;
    if ((t & 63) < 16) {
#pragma unroll
        for (int k = 0; k < 8; ++k) part[wave][g * 8 + k] = acc[k];
    }
    __syncthreads();

    if (t < HIDDEN) {
        float s = 0.f;
#pragma unroll
        for (int w = 0; w < 8; ++w) s += part[w][t];
        out[(size_t)b * HIDDEN + t] = s + bias[t];
    }
}

// Fallback (ws too small): direct strided gather from original W layout.
__global__ __launch_bounds__(HIDDEN) void bag_direct_kernel(
    const int* __restrict__ ids, const float* __restrict__ W,
    const float* __restrict__ bias, float* __restrict__ out) {
    __shared__ int sid[LEN];
    const int b = blockIdx.x;
    const int h = threadIdx.x;
    for (int l = h; l < LEN; l += HIDDEN) sid[l] = ids[b * LEN + l];
    __syncthreads();
    float acc = 0.f;
    for (int l = 0; l < LEN; ++l)
        acc += W[(size_t)h * VOCAB + sid[l]];
    out[(size_t)b * HIDDEN + h] = acc + bias[h];
}

extern "C" void kernel_launch(void* const* d_in, const int* in_sizes, int n_in,
                              void* d_out, int out_size, void* d_ws, size_t ws_size,
                              hipStream_t stream) {
    const int*   ids  = (const int*)d_in[0];
    const float* W    = (const float*)d_in[1];
    const float* bias = (const float*)d_in[2];
    float*       out  = (float*)d_out;

    const size_t need = (size_t)VOCAB * HIDDEN * sizeof(__half);
    if (ws_size >= need) {
        __half* WT = (__half*)d_ws;
        // Each kernel launched TWICE (idempotent) — dur_us delta vs the
        // single-launch round isolates the true kernel-sum from harness
        // restore/poison overhead.
        wt_transpose_f16<<<(VOCAB + TP_V - 1) / TP_V, 512, 0, stream>>>(W, WT);
        wt_transpose_f16<<<(VOCAB + TP_V - 1) / TP_V, 512, 0, stream>>>(W, WT);
        bag_gather_f16<<<BATCH, 512, 0, stream>>>(ids, WT, bias, out);
        bag_gather_f16<<<BATCH, 512, 0, stream>>>(ids, WT, bias, out);
    } else {
        bag_direct_kernel<<<BATCH, HIDDEN, 0, stream>>>(ids, W, bias, out);
    }
}

// Round 10
// 105.168 us; speedup vs baseline: 1.2646x; 1.2646x over previous
//
#include <hip/hip_runtime.h>
#include <hip/hip_fp16.h>

#define VOCAB 100000
#define HIDDEN 128
#define BATCH 1024
#define LEN 200
#define TP_V 128   // vocab-tile: 782 blocks -> ~3.05 blocks/CU, balanced

typedef float f32x4 __attribute__((ext_vector_type(4)));

// ---------------------------------------------------------------------------
// Kernel 1: transpose + downconvert  W f32 [HIDDEN][VOCAB] -> WT fp16 [VOCAB][HIDDEN]
// Round-8 doubling experiment showed T+G ~= 25.3us total and ~82us fixed
// harness overhead; the lever left is transpose load-balance:
//   TP_V=256 -> 391 blocks, 64KB LDS, 2/CU: 135 CUs pull 2 tiles, 121 pull 1
//   TP_V=128 -> 782 blocks, 32KB LDS, 3/CU co-resident, near-balanced.
// Swizzle: tile[v][h ^ ((v>>2)<<1)], banks (h>>1)^(v>>2):
//   - write phase (fixed h, vq4=v>>2 spans 0..31 across 32 lanes): all 32
//     banks, 2 lanes/bank over the wave = free.
//   - pack-read phase: <=4-way, minor (HBM-bound kernel).
// ---------------------------------------------------------------------------
__global__ __launch_bounds__(512) void wt_transpose_f16(
    const float* __restrict__ W, __half* __restrict__ WT) {
    __shared__ __half tile[TP_V][HIDDEN];
    const int v0 = blockIdx.x * TP_V;
    const int t  = threadIdx.x;

    // Read phase: vq4 = float4 slot along v (32 x 4 = 128 v), hr = h sub-row.
    const int vq4 = t & 31;
    const int hr  = t >> 5;    // 0..15
#pragma unroll
    for (int p = 0; p < 8; ++p) {
        const int h  = p * 16 + hr;
        const int gv = v0 + vq4 * 4;
        f32x4 f;
        if (gv + 3 < VOCAB) {
            f = __builtin_nontemporal_load(
                reinterpret_cast<const f32x4*>(&W[(size_t)h * VOCAB + gv]));
        } else {
            f[0] = (gv + 0 < VOCAB) ? W[(size_t)h * VOCAB + gv + 0] : 0.f;
            f[1] = (gv + 1 < VOCAB) ? W[(size_t)h * VOCAB + gv + 1] : 0.f;
            f[2] = (gv + 2 < VOCAB) ? W[(size_t)h * VOCAB + gv + 2] : 0.f;
            f[3] = (gv + 3 < VOCAB) ? W[(size_t)h * VOCAB + gv + 3] : 0.f;
        }
        const int sw = vq4 << 1;               // ((v>>2)&31)<<1, v=vq4*4+k
#pragma unroll
        for (int k = 0; k < 4; ++k) {
            tile[vq4 * 4 + k][h ^ sw] = __float2half_rn(f[k]);
        }
    }
    __syncthreads();

    // Store phase: c = 16B chunk of the 256 B output row, vr+32q = v row.
    const int c  = t & 15;
    const int vr = t >> 4;     // 0..31
#pragma unroll
    for (int q = 0; q < 4; ++q) {
        const int v  = vr + q * 32;
        const int gv = v0 + v;
        if (gv < VOCAB) {
            __half hb[8];
            const int sw = (v >> 2) << 1;
#pragma unroll
            for (int j = 0; j < 8; ++j) hb[j] = tile[v][(c * 8 + j) ^ sw];
            *reinterpret_cast<float4*>(&WT[(size_t)gv * HIDDEN + c * 8]) =
                *reinterpret_cast<const float4*>(hb);
        }
    }
}

// ---------------------------------------------------------------------------
// Kernel 2: gather-sum from fp16 WT.  UNCHANGED from the measured round-7/8
// version (one block per batch row, 512 threads, predicated unroll-7,
// 2x shfl_xor fold + part[8][128] + fused bias).
// ---------------------------------------------------------------------------
__global__ __launch_bounds__(512) void bag_gather_f16(
    const int* __restrict__ ids, const __half* __restrict__ WT,
    const float* __restrict__ bias, float* __restrict__ out) {
    __shared__ int   sid[LEN];
    __shared__ float part[8][HIDDEN];   // 4 KB

    const int b = blockIdx.x;
    const int t = threadIdx.x;

    for (int l = t; l < LEN; l += 512) sid[l] = ids[b * LEN + l];
    __syncthreads();

    const int g     = t & 15;
    const int chunk = t >> 4;

    float acc[8];
#pragma unroll
    for (int k = 0; k < 8; ++k) acc[k] = 0.f;

#pragma unroll
    for (int i = 0; i < 7; ++i) {
        const int  l  = chunk + i * 32;
        const bool ok = (l < LEN);
        const int  id = ok ? sid[l] : 0;
        const float4 q = *reinterpret_cast<const float4*>(
            WT + (size_t)id * HIDDEN + g * 8);
        if (ok) {
            const __half2* h2 = reinterpret_cast<const __half2*>(&q);
#pragma unroll
            for (int k = 0; k < 4; ++k) {
                const float2 f = __half22float2(h2[k]);
                acc[2 * k + 0] += f.x;
                acc[2 * k + 1] += f.y;
            }
        }
    }

#pragma unroll
    for (int k = 0; k < 8; ++k) {
        acc[k] += __shfl_xor(acc[k], 16);
        acc[k] += __shfl_xor(acc[k], 32);
    }
    const int wave = t >> 6;
    if ((t & 63) < 16) {
#pragma unroll
        for (int k = 0; k < 8; ++k) part[wave][g * 8 + k] = acc[k];
    }
    __syncthreads();

    if (t < HIDDEN) {
        float s = 0.f;
#pragma unroll
        for (int w = 0; w < 8; ++w) s += part[w][t];
        out[(size_t)b * HIDDEN + t] = s + bias[t];
    }
}

// ---------------------------------------------------------------------------
// Fallback (ws too small): direct strided gather from original W layout.
// ---------------------------------------------------------------------------
__global__ __launch_bounds__(HIDDEN) void bag_direct_kernel(
    const int* __restrict__ ids, const float* __restrict__ W,
    const float* __restrict__ bias, float* __restrict__ out) {
    __shared__ int sid[LEN];
    const int b = blockIdx.x;
    const int h = threadIdx.x;
    for (int l = h; l < LEN; l += HIDDEN) sid[l] = ids[b * LEN + l];
    __syncthreads();
    float acc = 0.f;
    for (int l = 0; l < LEN; ++l)
        acc += W[(size_t)h * VOCAB + sid[l]];
    out[(size_t)b * HIDDEN + h] = acc + bias[h];
}

extern "C" void kernel_launch(void* const* d_in, const int* in_sizes, int n_in,
                              void* d_out, int out_size, void* d_ws, size_t ws_size,
                              hipStream_t stream) {
    const int*   ids  = (const int*)d_in[0];
    const float* W    = (const float*)d_in[1];
    const float* bias = (const float*)d_in[2];
    float*       out  = (float*)d_out;

    const size_t need = (size_t)VOCAB * HIDDEN * sizeof(__half);
    if (ws_size >= need) {
        __half* WT = (__half*)d_ws;
        wt_transpose_f16<<<(VOCAB + TP_V - 1) / TP_V, 512, 0, stream>>>(W, WT);
        bag_gather_f16<<<BATCH, 512, 0, stream>>>(ids, WT, bias, out);
    } else {
        bag_direct_kernel<<<BATCH, HIDDEN, 0, stream>>>(ids, W, bias, out);
    }
}